// Round 1
// baseline (775.204 us; speedup 1.0000x reference)
//
#include <hip/hip_runtime.h>
#include <cstdint>
#include <cstddef>

#define DIM 2048
#define NHEADS 16
#define HD 128
#define BATCH 4
#define SEQ 2048
#define MROWS (BATCH*SEQ)   // 8192

typedef __attribute__((ext_vector_type(4))) float  f32x4;
typedef __attribute__((ext_vector_type(4))) float  float4v;
typedef __attribute__((ext_vector_type(8))) short  short8;
typedef __attribute__((ext_vector_type(4))) short  short4v;
typedef __attribute__((ext_vector_type(4))) unsigned uint4v;
typedef __attribute__((ext_vector_type(8))) __bf16 bf16x8;

__device__ __forceinline__ unsigned f2bfbits(float f) {
  unsigned u = __builtin_bit_cast(unsigned, f);
  return (u + 0x7FFFu + ((u >> 16) & 1u)) >> 16;
}
__device__ __forceinline__ short f2bf(float f) { return (short)f2bfbits(f); }
__device__ __forceinline__ float bf2f(short s) {
  unsigned u = ((unsigned)(unsigned short)s) << 16;
  return __builtin_bit_cast(float, u);
}
__device__ __forceinline__ f32x4 mfma16(short8 a, short8 b, f32x4 c) {
  return __builtin_amdgcn_mfma_f32_16x16x32_bf16(
      __builtin_bit_cast(bf16x8, a), __builtin_bit_cast(bf16x8, b), c, 0, 0, 0);
}

// ---------------------------------------------------------------- prep: x -> bf16
__global__ __launch_bounds__(256) void k_convert_x(const float* __restrict__ x,
                                                   short* __restrict__ xb) {
  size_t i = ((size_t)blockIdx.x * 256 + threadIdx.x) * 8;
  float4v a = *(const float4v*)(x + i);
  float4v b = *(const float4v*)(x + i + 4);
  short8 o;
  o[0] = f2bf(a[0]); o[1] = f2bf(a[1]); o[2] = f2bf(a[2]); o[3] = f2bf(a[3]);
  o[4] = f2bf(b[0]); o[5] = f2bf(b[1]); o[6] = f2bf(b[2]); o[7] = f2bf(b[3]);
  *(short8*)(xb + i) = o;
}

// ------------------------------------------------- prep: W [K][N] f32 -> Wt [N][K] bf16
__global__ __launch_bounds__(256) void k_transpose_w(
    const float* __restrict__ w0, const float* __restrict__ w1,
    const float* __restrict__ w2, const float* __restrict__ w3,
    short* __restrict__ o0, short* __restrict__ o1,
    short* __restrict__ o2, short* __restrict__ o3) {
  const float* w; short* o;
  switch (blockIdx.z) {
    case 0: w = w0; o = o0; break;
    case 1: w = w1; o = o1; break;
    case 2: w = w2; o = o2; break;
    default: w = w3; o = o3; break;
  }
  __shared__ float tile[32][33];
  int tx = threadIdx.x, ty = threadIdx.y;          // 32 x 8
  int kb = blockIdx.y * 32, nb = blockIdx.x * 32;
#pragma unroll
  for (int i = 0; i < 4; ++i)
    tile[ty + 8 * i][tx] = w[(size_t)(kb + ty + 8 * i) * DIM + nb + tx];
  __syncthreads();
#pragma unroll
  for (int i = 0; i < 4; ++i)
    o[(size_t)(nb + ty + 8 * i) * DIM + kb + tx] = f2bf(tile[tx][ty + 8 * i]);
}

// ---------------------------------------------------------------- GEMM
// C[M=8192][N=2048] = A[M][K=2048] (bf16) @ Bt[N][K] (bf16)^T
// MODE 0: bf16 out scattered to (B,H,S,D)     (q, k)
// MODE 1: bf16 out scattered to (B,H,D,S)     (v, pre-transposed)
// MODE 2: f32 out row-major [M][N]            (final projection)
template<int MODE>
__global__ __launch_bounds__(256) void k_gemm(const short* __restrict__ A,
                                              const short* __restrict__ Bt,
                                              void* __restrict__ outp) {
  __shared__ short As[128][72];
  __shared__ short Bs[128][72];
  const int t = threadIdx.x;
  const int lane = t & 63, wid = t >> 6;
  const int wm = wid >> 1, wn = wid & 1;
  const int gi = lane >> 4, li = lane & 15;
  const int m0 = blockIdx.y * 128, n0 = blockIdx.x * 128;

  f32x4 acc[4][4];
#pragma unroll
  for (int i = 0; i < 4; ++i)
#pragma unroll
    for (int j = 0; j < 4; ++j) acc[i][j] = (f32x4){0.f, 0.f, 0.f, 0.f};

  for (int k0 = 0; k0 < DIM; k0 += 64) {
#pragma unroll
    for (int i = 0; i < 4; ++i) {
      int idx = i * 256 + t;
      int r = idx >> 3, c = (idx & 7) * 8;
      *(short8*)&As[r][c] = *(const short8*)(A + (size_t)(m0 + r) * DIM + k0 + c);
      *(short8*)&Bs[r][c] = *(const short8*)(Bt + (size_t)(n0 + r) * DIM + k0 + c);
    }
    __syncthreads();
#pragma unroll
    for (int kk = 0; kk < 2; ++kk) {
      short8 av[4], bv[4];
#pragma unroll
      for (int i = 0; i < 4; ++i) {
        av[i] = *(const short8*)&As[64 * wm + 16 * i + li][kk * 32 + 8 * gi];
        bv[i] = *(const short8*)&Bs[64 * wn + 16 * i + li][kk * 32 + 8 * gi];
      }
#pragma unroll
      for (int i = 0; i < 4; ++i)
#pragma unroll
        for (int j = 0; j < 4; ++j)
          acc[i][j] = mfma16(av[i], bv[j], acc[i][j]);
    }
    __syncthreads();
  }

  if (MODE == 2) {
    float* O = (float*)outp;
#pragma unroll
    for (int i = 0; i < 4; ++i)
#pragma unroll
      for (int j = 0; j < 4; ++j)
#pragma unroll
        for (int r = 0; r < 4; ++r) {
          int gm = m0 + 64 * wm + 16 * i + 4 * gi + r;
          int gn = n0 + 64 * wn + 16 * j + li;
          O[(size_t)gm * DIM + gn] = acc[i][j][r];
        }
  } else if (MODE == 0) {
    short* O = (short*)outp;
#pragma unroll
    for (int i = 0; i < 4; ++i)
#pragma unroll
      for (int j = 0; j < 4; ++j)
#pragma unroll
        for (int r = 0; r < 4; ++r) {
          int gm = m0 + 64 * wm + 16 * i + 4 * gi + r;
          int gn = n0 + 64 * wn + 16 * j + li;
          int b = gm >> 11, s = gm & 2047, h = gn >> 7, d = gn & 127;
          O[((size_t)(b * NHEADS + h) * SEQ + s) * HD + d] = f2bf(acc[i][j][r]);
        }
  } else {  // MODE 1: (B,H,D,S), 4 consecutive s pack to one 8B store
    short* O = (short*)outp;
#pragma unroll
    for (int i = 0; i < 4; ++i)
#pragma unroll
      for (int j = 0; j < 4; ++j) {
        int gm0 = m0 + 64 * wm + 16 * i + 4 * gi;
        int gn = n0 + 64 * wn + 16 * j + li;
        int b = gm0 >> 11, s0 = gm0 & 2047, h = gn >> 7, d = gn & 127;
        short4v pk;
#pragma unroll
        for (int r = 0; r < 4; ++r) pk[r] = f2bf(acc[i][j][r]);
        *(short4v*)&O[((size_t)(b * NHEADS + h) * HD + d) * SEQ + s0] = pk;
      }
  }
}

// ---------------------------------------------------------------- RoPE in-place on Q,K (B,H,S,D)
__global__ __launch_bounds__(256) void k_rope(short* __restrict__ Q, short* __restrict__ K,
                                              const float* __restrict__ cosg,
                                              const float* __restrict__ sing) {
  int gid = blockIdx.x * 256 + threadIdx.x;       // 64*2048*16
  int bh = gid >> 15, rem = gid & 32767;
  int s = rem >> 4, dg = rem & 15;
  size_t base = ((size_t)bh * SEQ + s) * HD + dg * 4;
  float4v c = *(const float4v*)(cosg + s * 64 + dg * 4);
  float4v sn = *(const float4v*)(sing + s * 64 + dg * 4);
  short4v q1 = *(short4v*)(Q + base), q2 = *(short4v*)(Q + base + 64);
  short4v k1 = *(short4v*)(K + base), k2 = *(short4v*)(K + base + 64);
  short4v oq1, oq2, ok1, ok2;
#pragma unroll
  for (int j = 0; j < 4; ++j) {
    float a = bf2f(q1[j]), b = bf2f(q2[j]);
    oq1[j] = f2bf(a * c[j] - b * sn[j]);
    oq2[j] = f2bf(b * c[j] + a * sn[j]);
    float ak = bf2f(k1[j]), bk = bf2f(k2[j]);
    ok1[j] = f2bf(ak * c[j] - bk * sn[j]);
    ok2[j] = f2bf(bk * c[j] + ak * sn[j]);
  }
  *(short4v*)(Q + base) = oq1; *(short4v*)(Q + base + 64) = oq2;
  *(short4v*)(K + base) = ok1; *(short4v*)(K + base + 64) = ok2;
}

// ---------------------------------------------------------------- causal flash attention
// Q,K: (B,H,S,D) bf16 roped; V: (B,H,D,S) bf16; O: (B,S,H*D) bf16
// grid (S/64, B*H), 256 thr = 4 waves x 16 q-rows. Computes S^T = mfma(K, Q),
// so softmax stats live at col = lane&15; PV computes O^T = mfma(V^T, P^T).
__global__ __launch_bounds__(256) void k_flash(const short* __restrict__ Qg,
                                               const short* __restrict__ Kg,
                                               const short* __restrict__ Vg,
                                               short* __restrict__ Og) {
  __shared__ short Ks[64][136];
  __shared__ short Vs[128][72];
  const int t = threadIdx.x, lane = t & 63, wid = t >> 6;
  const int gi = lane >> 4, li = lane & 15;
  const int bh = blockIdx.y, q0 = blockIdx.x * 64;
  const short* Qb = Qg + (size_t)bh * SEQ * HD;
  const short* Kb = Kg + (size_t)bh * SEQ * HD;
  const short* Vb = Vg + (size_t)bh * HD * SEQ;
  const int mrow = q0 + wid * 16 + li;            // this lane's q row

  short8 qb[4];
#pragma unroll
  for (int kk = 0; kk < 4; ++kk)
    qb[kk] = *(const short8*)(Qb + (size_t)mrow * HD + kk * 32 + 8 * gi);

  f32x4 o[8];
#pragma unroll
  for (int d = 0; d < 8; ++d) o[d] = (f32x4){0.f, 0.f, 0.f, 0.f};
  float mx = -1e30f, lsum = 0.f;
  const int nt = blockIdx.x + 1;
  const int srcA = li | ((lane & 16) << 1);       // (m, 2*(g&1))
  const int srcB = srcA + 16;
  const bool hig = (lane & 32) != 0;

  for (int tt = 0; tt < nt; ++tt) {
    const int k0 = tt * 64;
#pragma unroll
    for (int i = 0; i < 4; ++i) {
      int idx = i * 256 + t;
      { int r = idx >> 4, c = (idx & 15) * 8;
        *(short8*)&Ks[r][c] = *(const short8*)(Kb + (size_t)(k0 + r) * HD + c); }
      { int r = idx >> 3, c = (idx & 7) * 8;
        *(short8*)&Vs[r][c] = *(const short8*)(Vb + (size_t)r * SEQ + k0 + c); }
    }
    __syncthreads();

    f32x4 sacc[4];
#pragma unroll
    for (int af = 0; af < 4; ++af) sacc[af] = (f32x4){0.f, 0.f, 0.f, 0.f};
#pragma unroll
    for (int kk = 0; kk < 4; ++kk)
#pragma unroll
      for (int af = 0; af < 4; ++af) {
        short8 kf = *(const short8*)&Ks[16 * af + li][kk * 32 + 8 * gi];
        sacc[af] = mfma16(kf, qb[kk], sacc[af]);
      }

    const float sc = 0.08838834764831843f;        // 1/sqrt(128)
    float p[4][4];
    float pmax = -1e30f;
    const bool last = (tt == nt - 1);
#pragma unroll
    for (int af = 0; af < 4; ++af)
#pragma unroll
      for (int r = 0; r < 4; ++r) {
        float v = sacc[af][r] * sc;
        if (last && (k0 + 16 * af + 4 * gi + r > mrow)) v = -1e30f;
        p[af][r] = v;
        pmax = fmaxf(pmax, v);
      }
    pmax = fmaxf(pmax, __shfl_xor(pmax, 16));
    pmax = fmaxf(pmax, __shfl_xor(pmax, 32));
    float mnew = fmaxf(mx, pmax);
    float alpha = __expf(mx - mnew);
    float psum = 0.f;
#pragma unroll
    for (int af = 0; af < 4; ++af)
#pragma unroll
      for (int r = 0; r < 4; ++r) {
        float e = __expf(p[af][r] - mnew);
        p[af][r] = e;
        psum += e;
      }
    psum += __shfl_xor(psum, 16);
    psum += __shfl_xor(psum, 32);
    lsum = lsum * alpha + psum;
    mx = mnew;
#pragma unroll
    for (int d = 0; d < 8; ++d) o[d] *= alpha;

    unsigned plo[4], phi[4];
#pragma unroll
    for (int af = 0; af < 4; ++af) {
      plo[af] = f2bfbits(p[af][0]) | (f2bfbits(p[af][1]) << 16);
      phi[af] = f2bfbits(p[af][2]) | (f2bfbits(p[af][3]) << 16);
    }
#pragma unroll
    for (int kk2 = 0; kk2 < 2; ++kk2) {
      unsigned aAlo = (unsigned)__shfl((int)plo[2 * kk2], srcA);
      unsigned aAhi = (unsigned)__shfl((int)phi[2 * kk2], srcA);
      unsigned aBlo = (unsigned)__shfl((int)plo[2 * kk2 + 1], srcA);
      unsigned aBhi = (unsigned)__shfl((int)phi[2 * kk2 + 1], srcA);
      unsigned bAlo = (unsigned)__shfl((int)plo[2 * kk2], srcB);
      unsigned bAhi = (unsigned)__shfl((int)phi[2 * kk2], srcB);
      unsigned bBlo = (unsigned)__shfl((int)plo[2 * kk2 + 1], srcB);
      unsigned bBhi = (unsigned)__shfl((int)phi[2 * kk2 + 1], srcB);
      uint4v dws;
      dws[0] = hig ? aBlo : aAlo;
      dws[1] = hig ? aBhi : aAhi;
      dws[2] = hig ? bBlo : bAlo;
      dws[3] = hig ? bBhi : bAhi;
      short8 pbf = __builtin_bit_cast(short8, dws);
#pragma unroll
      for (int d = 0; d < 8; ++d) {
        short8 vf = *(const short8*)&Vs[16 * d + li][kk2 * 32 + 8 * gi];
        o[d] = mfma16(vf, pbf, o[d]);
      }
    }
    __syncthreads();
  }

  const float inv = 1.0f / lsum;
  const int b = bh >> 4, h = bh & 15;
  const size_t obase = ((size_t)b * SEQ + mrow) * DIM + h * HD;
#pragma unroll
  for (int d = 0; d < 8; ++d) {
    short4v st;
#pragma unroll
    for (int r = 0; r < 4; ++r) st[r] = f2bf(o[d][r] * inv);
    *(short4v*)&Og[obase + d * 16 + 4 * gi] = st;
  }
}

// ---------------------------------------------------------------- launcher
extern "C" void kernel_launch(void* const* d_in, const int* in_sizes, int n_in,
                              void* d_out, int out_size, void* d_ws, size_t ws_size,
                              hipStream_t stream) {
  (void)in_sizes; (void)n_in; (void)out_size;
  const float* x    = (const float*)d_in[0];
  const float* cosg = (const float*)d_in[1];
  const float* sing = (const float*)d_in[2];
  const float* wq   = (const float*)d_in[3];
  const float* wk   = (const float*)d_in[4];
  const float* wv   = (const float*)d_in[5];
  const float* wo   = (const float*)d_in[6];

  const size_t SZ = (size_t)MROWS * DIM * 2;      // 33,554,432 B
  char* ws = (char*)d_ws;
  short* xb  = (short*)ws;                        // region 0, later reused as attn-out O
  short* wqT = (short*)(ws + SZ);
  short* wkT = wqT + (size_t)DIM * DIM;
  short* wvT = wkT + (size_t)DIM * DIM;
  short* woT = wvT + (size_t)DIM * DIM;
  short *Qp, *Kp, *Vp;
  if (ws_size >= 5 * SZ) {
    Qp = (short*)(ws + 2 * SZ);
    Kp = (short*)(ws + 3 * SZ);
    Vp = (short*)(ws + 4 * SZ);
  } else {                                        // park Q,K in d_out (overwritten at the end)
    Qp = (short*)d_out;
    Kp = (short*)d_out + SZ / 2;
    Vp = (short*)(ws + 2 * SZ);
  }
  short* Ob = xb;                                 // alias: xb dead after QKV GEMMs

  k_convert_x<<<8192, 256, 0, stream>>>(x, xb);
  k_transpose_w<<<dim3(64, 64, 4), dim3(32, 8), 0, stream>>>(wq, wk, wv, wo,
                                                             wqT, wkT, wvT, woT);
  k_gemm<0><<<dim3(16, 64), 256, 0, stream>>>(xb, wqT, Qp);
  k_gemm<0><<<dim3(16, 64), 256, 0, stream>>>(xb, wkT, Kp);
  k_gemm<1><<<dim3(16, 64), 256, 0, stream>>>(xb, wvT, Vp);
  k_rope<<<8192, 256, 0, stream>>>(Qp, Kp, cosg, sing);
  k_flash<<<dim3(32, 64), 256, 0, stream>>>(Qp, Kp, Vp, Ob);
  k_gemm<2><<<dim3(16, 64), 256, 0, stream>>>(Ob, woT, d_out);
}